// Round 20
// baseline (1715.370 us; speedup 1.0000x reference)
//
#include <hip/hip_runtime.h>
#include <stdint.h>
#include <stddef.h>

#define B_ 64
#define L_ 200
#define F_ 512
#define H_ 512
#define A_ 512
#define E_ 512
#define V_ 50257
#define PADV 50304
#define T_ 21
#define D_ 1024
#define NBLK32 1572
#define BH (B_ * H_)
#define BD (B_ * D_)
#define NROW 1280
#define NBP 128        /* persistent recurrence blocks */

typedef __attribute__((ext_vector_type(8))) short short8;
typedef __attribute__((ext_vector_type(4))) float f32x4;

__device__ __forceinline__ unsigned short f2b(float f) {
  unsigned int u = __builtin_bit_cast(unsigned int, f);
  u += 0x7FFFu + ((u >> 16) & 1u);
  return (unsigned short)(u >> 16);
}
__device__ __forceinline__ float b2f(unsigned short s) {
  unsigned int u = ((unsigned int)s) << 16;
  return __builtin_bit_cast(float, u);
}
__device__ __forceinline__ f32x4 mfma16(short8 a, short8 b, f32x4 c) {
  return __builtin_amdgcn_mfma_f32_16x16x32_bf16(a, b, c, 0, 0, 0);
}
__device__ __forceinline__ int hsoff(int b, int j) {
  return (((b >> 4) * 16 + (j >> 5)) * 64 + (((j >> 3) & 3) * 16 + (b & 15))) * 8 + (j & 7);
}
__device__ __forceinline__ int xoff(int b, int k) {
  return (((b >> 4) * 32 + (k >> 5)) * 64 + (((k >> 3) & 3) * 16 + (b & 15))) * 8 + (k & 7);
}

/* ---- coherent (IC-bypassing) access helpers: relaxed agent-scope atomics ---- */
__device__ __forceinline__ float aldf(const float* p) {
  return __hip_atomic_load(p, __ATOMIC_RELAXED, __HIP_MEMORY_SCOPE_AGENT);
}
__device__ __forceinline__ void astf(float* p, float v) {
  __hip_atomic_store(p, v, __ATOMIC_RELAXED, __HIP_MEMORY_SCOPE_AGENT);
}
__device__ __forceinline__ unsigned long long aldu(const void* p) {
  return __hip_atomic_load((const unsigned long long*)p, __ATOMIC_RELAXED, __HIP_MEMORY_SCOPE_AGENT);
}
__device__ __forceinline__ void astu(void* p, unsigned long long v) {
  __hip_atomic_store((unsigned long long*)p, v, __ATOMIC_RELAXED, __HIP_MEMORY_SCOPE_AGENT);
}
__device__ __forceinline__ short8 ald16(const unsigned short* p) {
  union { unsigned long long u[2]; short8 s; } t;
  t.u[0] = aldu(p);
  t.u[1] = aldu(p + 4);
  return t.s;
}

/* ---------------- setup device helpers ---------------- */

__device__ void cvt_dev(const float* __restrict__ src, unsigned short* __restrict__ dst,
                        int n4, int vbid, int nblk) {
  int i = vbid * 256 + threadIdx.x;
  int stride = nblk * 256;
  const float4* s4 = (const float4*)src;
  ushort4* d4 = (ushort4*)dst;
  for (; i < n4; i += stride) {
    float4 v = s4[i];
    ushort4 o;
    o.x = f2b(v.x); o.y = f2b(v.y); o.z = f2b(v.z); o.w = f2b(v.w);
    d4[i] = o;
  }
}

__device__ void wfrag_dev(const float* __restrict__ src, unsigned short* __restrict__ dst,
                          int K, int rt) {
  int r15 = threadIdx.x & 15;
  int row = rt * 16 + r15;
  int nch = K >> 3;
  int kpw = K >> 5;
  for (int kc = threadIdx.x >> 4; kc < nch; kc += 16) {
    const float4* s = (const float4*)(src + (size_t)row * K + kc * 8);
    float4 x = s[0], y = s[1];
    short8 o;
    o[0] = f2b(x.x); o[1] = f2b(x.y); o[2] = f2b(x.z); o[3] = f2b(x.w);
    o[4] = f2b(y.x); o[5] = f2b(y.y); o[6] = f2b(y.z); o[7] = f2b(y.w);
    *(short8*)(dst + ((size_t)(rt * kpw + (kc >> 2)) * 64 + ((kc & 3) * 16 + r15)) * 8) = o;
  }
}

/* ---------------- stage-A mega setup (r18 verified) ---------------- */
__global__ __launch_bounds__(256) void k_setupA(const float* __restrict__ Wout, unsigned short* __restrict__ Wb,
                                                const float* __restrict__ enc, unsigned short* __restrict__ encb,
                                                const float* __restrict__ Wih, unsigned short* __restrict__ Wfih,
                                                const float* __restrict__ Whh, unsigned short* __restrict__ Wfhh,
                                                const float* __restrict__ Waenc, unsigned short* __restrict__ WaTb,
                                                const float* __restrict__ Wah, float* __restrict__ WahT32,
                                                const float* __restrict__ dih, unsigned short* __restrict__ hsAll,
                                                const int* __restrict__ ref, const float* __restrict__ et,
                                                unsigned short* __restrict__ xAll) {
  __shared__ float tile[64][65];
  int bid = blockIdx.x;
  int tid = threadIdx.x;
  if (bid < 4096) {
    cvt_dev(Wout, Wb, V_ * H_ / 4, bid, 4096);
  } else if (bid < 6144) {
    cvt_dev(enc, encb, B_ * L_ * F_ / 4, bid - 4096, 2048);
  } else if (bid < 6240) {
    wfrag_dev(Wih, Wfih, 1024, bid - 6144);
  } else if (bid < 6336) {
    wfrag_dev(Whh, Wfhh, 512, bid - 6240);
  } else if (bid < 6400) {
    int q = bid - 6336;
    int cb = (q & 7) * 64, rb = (q >> 3) * 64;
    int tx = tid & 63, ty = tid >> 6;
#pragma unroll
    for (int i = 0; i < 16; ++i) {
      int r = ty * 16 + i;
      tile[r][tx] = Waenc[(size_t)(rb + r) * 512 + cb + tx];
    }
    __syncthreads();
#pragma unroll
    for (int i = 0; i < 16; ++i) {
      int c = ty * 16 + i;
      WaTb[(size_t)(cb + c) * 512 + rb + tx] = f2b(tile[tx][c]);
    }
  } else if (bid < 6464) {
    int q = bid - 6400;
    int cb = (q & 7) * 64, rb = (q >> 3) * 64;
    int tx = tid & 63, ty = tid >> 6;
#pragma unroll
    for (int i = 0; i < 16; ++i) {
      int r = ty * 16 + i;
      tile[r][tx] = Wah[(size_t)(rb + r) * 512 + cb + tx];
    }
    __syncthreads();
#pragma unroll
    for (int i = 0; i < 16; ++i) {
      int c = ty * 16 + i;
      WahT32[(size_t)(cb + c) * 512 + rb + tx] = tile[tx][c];
    }
  } else if (bid < 6528) {
    int b = bid - 6464;
    for (int j = tid; j < H_; j += 256)
      hsAll[hsoff(b, j)] = f2b(dih[(size_t)b * H_ + j]);
  } else {
    int q = bid - 6528;
    int b = q & 63, tp = q >> 6;
    if (tid < 64) {
      int word = ref[b * T_ + tp];
      const float* er = et + (size_t)word * E_;
      unsigned short* dst = xAll + (size_t)tp * BD;
      int c = tid;
      const float4* s = (const float4*)(er + c * 8);
      float4 x = s[0], y = s[1];
      short8 o;
      o[0] = f2b(x.x); o[1] = f2b(x.y); o[2] = f2b(x.z); o[3] = f2b(x.w);
      o[4] = f2b(y.x); o[5] = f2b(y.y); o[6] = f2b(y.z); o[7] = f2b(y.w);
      *(short8*)(dst + xoff(b, c * 8)) = o;
    }
  }
}

/* ---------------- stage-B setup (r18 verified) + barrier counter zero ---------------- */
__global__ __launch_bounds__(256) void k_setupB(const float* __restrict__ WahT32,
                                                unsigned short* __restrict__ Wahf,
                                                const unsigned short* __restrict__ encb,
                                                const unsigned short* __restrict__ WaTb,
                                                unsigned short* __restrict__ epb,
                                                unsigned int* __restrict__ cnt) {
  __shared__ unsigned short al[32768];
  int bid = blockIdx.x;
  int tid = threadIdx.x;
  if (bid == 0 && tid == 0) *cnt = 0;
  if (bid < 32) {
    wfrag_dev(WahT32, Wahf, 512, bid);
    return;
  }
  size_t rowbase = (size_t)(bid - 32) * 64;
  for (int idx = tid; idx < 4096; idx += 256) {
    int row = idx >> 6, seg = idx & 63;
    unsigned char* dp = (unsigned char*)al + row * 1024 + ((seg * 16) ^ ((row & 7) << 4));
    *(short8*)dp = *(const short8*)(encb + (rowbase + row) * F_ + seg * 8);
  }
  __syncthreads();
  int w = tid >> 6, lane = tid & 63, ln15 = lane & 15, g = lane >> 4;
  int sw = (ln15 & 7) << 4;
  const unsigned char* alb = (const unsigned char*)al;
  int mrow = w * 16 + ln15;
  for (int nt = 0; nt < 32; ++nt) {
    f32x4 acc = {0.f, 0.f, 0.f, 0.f};
    const unsigned short* brow = WaTb + (size_t)(nt * 16 + ln15) * F_ + 8 * g;
#pragma unroll 4
    for (int kk = 0; kk < 16; ++kk) {
      short8 bf = *(const short8*)(brow + kk * 32);
      short8 af = *(const short8*)(alb + mrow * 1024 + ((kk * 64 + 16 * g) ^ sw));
      acc = mfma16(af, bf, acc);
    }
#pragma unroll
    for (int r = 0; r < 4; ++r) {
      size_t m = rowbase + w * 16 + 4 * g + r;
      epb[m * A_ + nt * 16 + ln15] = f2b(acc[r]);
    }
  }
}

/* ---------------- persistent recurrence (no grid.sync; relaxed-atomic barrier) ---------------- */

struct RecPP {
  const float* mask; const float* vatt;
  const unsigned short* encb; const unsigned short* epb;
  const unsigned short* Wahf; const unsigned short* Wfhh; const unsigned short* Wfih;
  const float* bih; const float* bhh;
  const float* dih;
  unsigned short* hsAll; float* hBAll; unsigned short* xAll;
  float* hw; float* ghG;
  unsigned int* cnt;
};

__device__ __forceinline__ void gbar(unsigned int* cnt, unsigned int target) {
  __syncthreads();  // drains all waves' vmcnt -> dynamic stores at IC
  if (threadIdx.x == 0) {
    __hip_atomic_fetch_add(cnt, 1u, __ATOMIC_RELAXED, __HIP_MEMORY_SCOPE_AGENT);
    while (__hip_atomic_load(cnt, __ATOMIC_RELAXED, __HIP_MEMORY_SCOPE_AGENT) < target)
      __builtin_amdgcn_s_sleep(8);
  }
  __syncthreads();
}

__global__ __launch_bounds__(512) void k_rec2(RecPP P) {
  __shared__ float sm[208];
  __shared__ float ctxp[8][F_];
  __shared__ float ctxF[F_];
  int blk = blockIdx.x;
  int tid = threadIdx.x;
  unsigned int tgt = 0;

  for (int t = 0; t < T_ - 1; ++t) {
    const unsigned short* hs_t = P.hsAll + (size_t)t * BH;
    unsigned short* xp = P.xAll + (size_t)t * BD;
    /* ---- P1: hw (blk 0..31) || gh (blk 32..127) ; dynamic input hs via IC ---- */
    if (tid < 256) {
      int w = tid >> 6, lane = tid & 63, ln15 = lane & 15, g = lane >> 4;
      if (blk < 32) {
        f32x4 acc = {0.f, 0.f, 0.f, 0.f};
#pragma unroll 4
        for (int kk = 0; kk < 16; ++kk) {
          short8 av = *(const short8*)(P.Wahf + (((size_t)blk * 16 + kk) * 64 + lane) * 8);
          short8 hv = ald16(hs_t + (((size_t)w * 16 + kk) * 64 + lane) * 8);
          acc = mfma16(av, hv, acc);
        }
#pragma unroll
        for (int r = 0; r < 4; ++r)
          astf(P.hw + (size_t)(w * 16 + ln15) * 512 + blk * 16 + 4 * g + r, acc[r]);
      } else {
        int jt = blk - 32;
        f32x4 acc = {0.f, 0.f, 0.f, 0.f};
#pragma unroll 4
        for (int kk = 0; kk < 16; ++kk) {
          short8 wv = *(const short8*)(P.Wfhh + (((size_t)jt * 16 + kk) * 64 + lane) * 8);
          short8 hv = ald16(hs_t + (((size_t)w * 16 + kk) * 64 + lane) * 8);
          acc = mfma16(wv, hv, acc);
        }
#pragma unroll
        for (int r = 0; r < 4; ++r)
          astf(P.ghG + (size_t)(jt * 16 + 4 * g + r) * B_ + w * 16 + ln15, acc[r]);
      }
    }
    tgt += NBP; gbar(P.cnt, tgt);

    /* ---- P2: attention (blk 0..63, 8 waves) ; hw via IC, epb/encb cached ---- */
    if (blk < 64) {
      int b = blk;
      int w = tid >> 6, lane = tid & 63;
      float hwv[8], vv[8];
#pragma unroll
      for (int j = 0; j < 8; ++j) {
        hwv[j] = aldf(P.hw + (size_t)b * 512 + lane * 8 + j);
        vv[j] = P.vatt[lane * 8 + j];
      }
      for (int l = w; l < L_; l += 8) {
        short8 ev = *(const short8*)(P.epb + ((size_t)(b * L_ + l)) * 512 + lane * 8);
        float p = 0.f;
#pragma unroll
        for (int j = 0; j < 8; ++j) {
          float x = b2f((unsigned short)ev[j]) + hwv[j];
          float e2 = __expf(x + x);
          p = fmaf(1.f - 2.f / (e2 + 1.f), vv[j], p);
        }
        for (int o = 1; o < 64; o <<= 1) p += __shfl_xor(p, o);
        if (lane == 0) {
          float mk = P.mask[b * L_ + l];
          sm[l] = (mk > 0.f) ? p : -1e9f;
        }
      }
      __syncthreads();
      if (tid < 64) {
        float m = -1e30f;
        for (int l = tid; l < L_; l += 64) m = fmaxf(m, sm[l]);
        for (int o = 1; o < 64; o <<= 1) m = fmaxf(m, __shfl_xor(m, o));
        float s = 0.f;
        for (int l = tid; l < L_; l += 64) s += __expf(sm[l] - m);
        for (int o = 1; o < 64; o <<= 1) s += __shfl_xor(s, o);
        float inv = 1.f / s;
        for (int l = tid; l < L_; l += 64) sm[l] = __expf(sm[l] - m) * inv;
      }
      __syncthreads();
      float c[8] = {0.f, 0.f, 0.f, 0.f, 0.f, 0.f, 0.f, 0.f};
      for (int l = w; l < L_; l += 8) {
        float wgt = sm[l];
        short8 ev = *(const short8*)(P.encb + ((size_t)(b * L_ + l)) * 512 + lane * 8);
#pragma unroll
        for (int j = 0; j < 8; ++j) c[j] = fmaf(wgt, b2f((unsigned short)ev[j]), c[j]);
      }
#pragma unroll
      for (int j = 0; j < 8; ++j) ctxp[w][lane * 8 + j] = c[j];
      __syncthreads();
      if (tid < 512) {
        float s = 0.f;
#pragma unroll
        for (int q = 0; q < 8; ++q) s += ctxp[q][tid];
        ctxF[tid] = s;
      }
      __syncthreads();
      if (tid < 64) {
        unsigned long long lo = 0, hi = 0;
#pragma unroll
        for (int j = 0; j < 4; ++j) lo |= (unsigned long long)f2b(ctxF[tid * 8 + j]) << (16 * j);
#pragma unroll
        for (int j = 0; j < 4; ++j) hi |= (unsigned long long)f2b(ctxF[tid * 8 + 4 + j]) << (16 * j);
        unsigned short* dst = xp + xoff(b, E_ + tid * 8);
        astu(dst, lo);
        astu(dst + 4, hi);
      }
    }
    tgt += NBP; gbar(P.cnt, tgt);

    /* ---- P3: gi MFMA + gates (blk 0..31) ; x/ghG/hB via IC, Wfih cached ---- */
    if (blk < 32 && tid < 256) {
      int bx = blk;
      int w = tid >> 6, lane = tid & 63, ln15 = lane & 15, g = lane >> 4;
      const float* hBold = (t == 0) ? P.dih : (P.hBAll + (size_t)t * BH);
      float* hBnew = P.hBAll + (size_t)(t + 1) * BH;
      unsigned short* hsnew = P.hsAll + (size_t)(t + 1) * BH;
      f32x4 z4 = {0.f, 0.f, 0.f, 0.f};
      f32x4 aIr = z4, aIz = z4, aIn = z4;
#pragma unroll 2
      for (int kk = 0; kk < 32; ++kk) {
        short8 xv = ald16(xp + (((size_t)w * 32 + kk) * 64 + lane) * 8);
        aIr = mfma16(*(const short8*)(P.Wfih + (((size_t)(0 * 32 + bx) * 32 + kk) * 64 + lane) * 8), xv, aIr);
        aIz = mfma16(*(const short8*)(P.Wfih + (((size_t)(32 + bx) * 32 + kk) * 64 + lane) * 8), xv, aIz);
        aIn = mfma16(*(const short8*)(P.Wfih + (((size_t)(64 + bx) * 32 + kk) * 64 + lane) * 8), xv, aIn);
      }
      int jb = bx * 16;
      int b = w * 16 + ln15;
      unsigned long long pk = 0;
#pragma unroll
      for (int r = 0; r < 4; ++r) {
        int j = jb + 4 * g + r;
        float ir = aIr[r] + P.bih[j];
        float iz = aIz[r] + P.bih[512 + j];
        float in_ = aIn[r] + P.bih[1024 + j];
        float hrv = aldf(P.ghG + (size_t)j * B_ + b) + P.bhh[j];
        float hzv = aldf(P.ghG + (size_t)(512 + j) * B_ + b) + P.bhh[512 + j];
        float hnv = aldf(P.ghG + (size_t)(1024 + j) * B_ + b) + P.bhh[1024 + j];
        float rg = 1.f / (1.f + __expf(-(ir + hrv)));
        float zg = 1.f / (1.f + __expf(-(iz + hzv)));
        float e2 = __expf(2.f * (in_ + rg * hnv));
        float ng = 1.f - 2.f / (e2 + 1.f);
        float ho = aldf(hBold + (size_t)b * H_ + j);
        float hv = (1.f - zg) * ng + zg * ho;
        astf(hBnew + (size_t)b * H_ + j, hv);
        pk |= (unsigned long long)f2b(hv) << (16 * r);
      }
      astu(hsnew + hsoff(b, jb + 4 * g), pk);
    }
    tgt += NBP; gbar(P.cnt, tgt);
  }
}

/* ---------------- fallback per-step kernels (r19 verified, unchanged) ---------------- */

__global__ __launch_bounds__(256) void k_hwgh(const unsigned short* __restrict__ Wahf,
                                              const unsigned short* __restrict__ Wfhh,
                                              const unsigned short* __restrict__ hs,
                                              float* __restrict__ hw,
                                              float* __restrict__ ghG) {
  int blk = blockIdx.x;
  int w = threadIdx.x >> 6, lane = threadIdx.x & 63;
  int ln15 = lane & 15, g = lane >> 4;
  if (blk < 32) {
    f32x4 acc = {0.f, 0.f, 0.f, 0.f};
#pragma unroll 4
    for (int kk = 0; kk < 16; ++kk) {
      short8 av = *(const short8*)(Wahf + (((size_t)blk * 16 + kk) * 64 + lane) * 8);
      short8 hv = *(const short8*)(hs + (((size_t)w * 16 + kk) * 64 + lane) * 8);
      acc = mfma16(av, hv, acc);
    }
#pragma unroll
    for (int r = 0; r < 4; ++r)
      hw[(size_t)(w * 16 + ln15) * 512 + blk * 16 + 4 * g + r] = acc[r];
  } else {
    int jt = blk - 32;
    f32x4 acc = {0.f, 0.f, 0.f, 0.f};
#pragma unroll
    for (int kk = 0; kk < 16; ++kk) {
      short8 wv = *(const short8*)(Wfhh + (((size_t)jt * 16 + kk) * 64 + lane) * 8);
      short8 hv = *(const short8*)(hs + (((size_t)w * 16 + kk) * 64 + lane) * 8);
      acc = mfma16(wv, hv, acc);
    }
#pragma unroll
    for (int r = 0; r < 4; ++r)
      ghG[(size_t)(jt * 16 + 4 * g + r) * B_ + w * 16 + ln15] = acc[r];
  }
}

__global__ __launch_bounds__(1024) void k_attB(const float* __restrict__ mask,
                                               const float* __restrict__ vatt,
                                               const unsigned short* __restrict__ encb,
                                               const unsigned short* __restrict__ epb,
                                               const float* __restrict__ hw,
                                               unsigned short* __restrict__ xplane) {
  __shared__ float sm[208];
  __shared__ float ctxp[16][F_];
  __shared__ float ctxF[F_];
  int b = blockIdx.x;
  int tid = threadIdx.x;
  int w = tid >> 6, lane = tid & 63;
  float hwv[8], vv[8];
  {
    const float4* hp = (const float4*)(hw + (size_t)b * 512 + lane * 8);
    const float4* vp = (const float4*)(vatt + lane * 8);
    float4 h0 = hp[0], h1 = hp[1], v0 = vp[0], v1 = vp[1];
    hwv[0] = h0.x; hwv[1] = h0.y; hwv[2] = h0.z; hwv[3] = h0.w;
    hwv[4] = h1.x; hwv[5] = h1.y; hwv[6] = h1.z; hwv[7] = h1.w;
    vv[0] = v0.x; vv[1] = v0.y; vv[2] = v0.z; vv[3] = v0.w;
    vv[4] = v1.x; vv[5] = v1.y; vv[6] = v1.z; vv[7] = v1.w;
  }
  for (int l = w; l < L_; l += 16) {
    short8 ev = *(const short8*)(epb + ((size_t)(b * L_ + l)) * 512 + lane * 8);
    float p = 0.f;
#pragma unroll
    for (int j = 0; j < 8; ++j) {
      float x = b2f((unsigned short)ev[j]) + hwv[j];
      float e2 = __expf(x + x);
      p = fmaf(1.f - 2.f / (e2 + 1.f), vv[j], p);
    }
    for (int o = 1; o < 64; o <<= 1) p += __shfl_xor(p, o);
    if (lane == 0) {
      float mk = mask[b * L_ + l];
      sm[l] = (mk > 0.f) ? p : -1e9f;
    }
  }
  __syncthreads();
  if (tid < 64) {
    float m = -1e30f;
    for (int l = tid; l < L_; l += 64) m = fmaxf(m, sm[l]);
    for (int o = 1; o < 64; o <<= 1) m = fmaxf(m, __shfl_xor(m, o));
    float s = 0.f;
    for (int l = tid; l < L_; l += 64) s += __expf(sm[l] - m);
    for (int o = 1; o < 64; o <<= 1) s += __shfl_xor(s, o);
    float inv = 1.f / s;
    for (int l = tid; l < L_; l += 64) sm[l] = __expf(sm[l] - m) * inv;
  }
  __syncthreads();
  float c[8] = {0.f, 0.f, 0.f, 0.f, 0.f, 0.f, 0.f, 0.f};
  for (int l = w; l < L_; l += 16) {
    float wgt = sm[l];
    short8 ev = *(const short8*)(encb + ((size_t)(b * L_ + l)) * 512 + lane * 8);
#pragma unroll
    for (int j = 0; j < 8; ++j) c[j] = fmaf(wgt, b2f((unsigned short)ev[j]), c[j]);
  }
#pragma unroll
  for (int j = 0; j < 8; ++j) ctxp[w][lane * 8 + j] = c[j];
  __syncthreads();
  if (tid < 512) {
    float s = 0.f;
#pragma unroll
    for (int q = 0; q < 16; ++q) s += ctxp[q][tid];
    ctxF[tid] = s;
  }
  __syncthreads();
  if (tid < 64) {
    short8 o;
#pragma unroll
    for (int j = 0; j < 8; ++j) o[j] = f2b(ctxF[tid * 8 + j]);
    *(short8*)(xplane + xoff(b, E_ + tid * 8)) = o;
  }
}

__global__ __launch_bounds__(256) void k_stepB(const unsigned short* __restrict__ Wfih,
                                               const float* __restrict__ bih,
                                               const float* __restrict__ bhh,
                                               const unsigned short* __restrict__ xplane,
                                               const float* __restrict__ ghG,
                                               const float* __restrict__ hBold,
                                               unsigned short* __restrict__ hsnew,
                                               float* __restrict__ hBnew) {
  int bx = blockIdx.x;
  int w = threadIdx.x >> 6, lane = threadIdx.x & 63;
  int ln15 = lane & 15, g = lane >> 4;
  f32x4 z4 = {0.f, 0.f, 0.f, 0.f};
  f32x4 aIr = z4, aIz = z4, aIn = z4;
#pragma unroll 2
  for (int kk = 0; kk < 32; ++kk) {
    short8 xv = *(const short8*)(xplane + (((size_t)w * 32 + kk) * 64 + lane) * 8);
    aIr = mfma16(*(const short8*)(Wfih + (((size_t)(0 * 32 + bx) * 32 + kk) * 64 + lane) * 8), xv, aIr);
    aIz = mfma16(*(const short8*)(Wfih + (((size_t)(32 + bx) * 32 + kk) * 64 + lane) * 8), xv, aIz);
    aIn = mfma16(*(const short8*)(Wfih + (((size_t)(64 + bx) * 32 + kk) * 64 + lane) * 8), xv, aIn);
  }
  int jb = bx * 16;
#pragma unroll
  for (int r = 0; r < 4; ++r) {
    int j = jb + 4 * g + r;
    int b = w * 16 + ln15;
    float ir = aIr[r] + bih[j];
    float iz = aIz[r] + bih[512 + j];
    float in_ = aIn[r] + bih[1024 + j];
    float hrv = ghG[(size_t)j * B_ + b] + bhh[j];
    float hzv = ghG[(size_t)(512 + j) * B_ + b] + bhh[512 + j];
    float hnv = ghG[(size_t)(1024 + j) * B_ + b] + bhh[1024 + j];
    float rg = 1.f / (1.f + __expf(-(ir + hrv)));
    float zg = 1.f / (1.f + __expf(-(iz + hzv)));
    float e2 = __expf(2.f * (in_ + rg * hnv));
    float ng = 1.f - 2.f / (e2 + 1.f);
    float ho = hBold[(size_t)b * H_ + j];
    float hv = (1.f - zg) * ng + zg * ho;
    hBnew[(size_t)b * H_ + j] = hv;
    hsnew[hsoff(b, j)] = f2b(hv);
  }
}

/* ---------------- logits GEMM: 32-col tiles, 1572 blocks (r19 verified) ---------------- */

__global__ __launch_bounds__(256) void k_blog(const unsigned short* __restrict__ Wb,
                                              const float* __restrict__ bout,
                                              const unsigned short* __restrict__ hsAll,
                                              float* __restrict__ out,
                                              unsigned short* __restrict__ lws, int mode) {
  __shared__ unsigned short tile[2][64][40];
  int tid = threadIdx.x;
  int w = tid >> 6, lane = tid & 63, ln15 = lane & 15, g = lane >> 4;
  int ch = w & 1, mh = w >> 1;
  int vcol = blockIdx.x * 32 + ch * 16 + ln15;
  bool vok = vcol < V_;
  int vr = vok ? vcol : (V_ - 1);
  const unsigned short* brow = Wb + (size_t)vr * H_ + 8 * g;
  short8 wb[16];
#pragma unroll
  for (int kk = 0; kk < 16; ++kk) wb[kk] = *(const short8*)(brow + kk * 32);
  float bo = bout[vr];
  int row = tid >> 2, seg = tid & 3;

  for (int t = 0; t < T_ - 1; ++t) {
    const unsigned short* hp = hsAll + (size_t)(t + 1) * BH;
    int buf = t & 1;
    __builtin_amdgcn_s_setprio(1);
    f32x4 z4 = {0.f, 0.f, 0.f, 0.f};
    f32x4 acc0 = z4, acc1 = z4;
#pragma unroll
    for (int kk = 0; kk < 16; ++kk) {
      short8 a0 = *(const short8*)(hp + (((mh * 2 + 0) * 16 + kk) * 64 + lane) * 8);
      short8 a1 = *(const short8*)(hp + (((mh * 2 + 1) * 16 + kk) * 64 + lane) * 8);
      acc0 = mfma16(a0, wb[kk], acc0);
      acc1 = mfma16(a1, wb[kk], acc1);
    }
    __builtin_amdgcn_s_setprio(0);
#pragma unroll
    for (int r = 0; r < 4; ++r) {
      int bi0 = (mh * 2 + 0) * 16 + 4 * g + r;
      int bi1 = (mh * 2 + 1) * 16 + 4 * g + r;
      int col = ch * 16 + ln15;
      tile[buf][bi0][col] = vok ? f2b(acc0[r] + bo) : f2b(-1e30f);
      tile[buf][bi1][col] = vok ? f2b(acc1[r] + bo) : f2b(-1e30f);
    }
    __syncthreads();
    int cb = blockIdx.x * 32 + seg * 8;
    if (mode == 1) {
      short8 sv = *(const short8*)&tile[buf][row][seg * 8];
      *(short8*)(lws + ((size_t)t * 64 + row) * PADV + cb) = sv;
    } else {
      short8 sv = *(const short8*)&tile[buf][row][seg * 8];
      float* orow = out + ((size_t)row * T_ + (t + 1)) * V_ + cb;
      if (cb + 8 <= V_) {
#pragma unroll
        for (int i = 0; i < 8; ++i) orow[i] = b2f((unsigned short)sv[i]);
      } else {
        for (int i = 0; i < 8; ++i)
          if (cb + i < V_) orow[i] = b2f((unsigned short)sv[i]);
      }
    }
  }
}

/* ---------------- fused LSE + finalize + plane0 zero (r16 verified) ---------------- */

__global__ __launch_bounds__(512) void k_lsefin(const unsigned short* __restrict__ lws,
                                                float* __restrict__ out) {
  __shared__ unsigned short srow[PADV];
  __shared__ float lm[512], ls[512];
  __shared__ float lvs;
  int bid = blockIdx.x;
  int tid = threadIdx.x;
  if (bid >= NROW) {
    int b = bid - NROW;
    float* o = out + (size_t)b * T_ * V_;
    float4 z = make_float4(0.f, 0.f, 0.f, 0.f);
    for (int i = tid; i < 12564; i += 512) *(float4*)(o + i * 4) = z;
    if (tid == 0) o[50256] = 0.f;
    return;
  }
  int rho = bid;
  int tp = rho >> 6, b = rho & 63;
  const unsigned short* src = lws + (size_t)(tp * 64 + b) * PADV;
  float* o = out + ((size_t)b * T_ + (tp + 1)) * V_;
  float m = -1e30f, s = 0.f;
  for (int i = tid; i < PADV / 8; i += 512) {
    short8 sv = *(const short8*)(src + i * 8);
    *(short8*)(srow + i * 8) = sv;
    float x0 = b2f((unsigned short)sv[0]), x1 = b2f((unsigned short)sv[1]);
    float x2 = b2f((unsigned short)sv[2]), x3 = b2f((unsigned short)sv[3]);
    float x4 = b2f((unsigned short)sv[4]), x5 = b2f((unsigned short)sv[5]);
    float x6 = b2f((unsigned short)sv[6]), x7 = b2f((unsigned short)sv[7]);
    float cm = fmaxf(fmaxf(fmaxf(x0, x1), fmaxf(x2, x3)), fmaxf(fmaxf(x4, x5), fmaxf(x6, x7)));
    float cs = __expf(x0 - cm) + __expf(x1 - cm) + __expf(x2 - cm) + __expf(x3 - cm) +
               __expf(x4 - cm) + __expf(x5 - cm) + __expf(x6 - cm) + __expf(x7 - cm);
    float nm = fmaxf(m, cm);
    s = s * __expf(m - nm) + cs * __expf(cm - nm);
    m = nm;
  }
  lm[tid] = m; ls[tid] = s;
  __syncthreads();
  for (int o2 = 256; o2 > 0; o2 >>= 1) {
    if (tid < o2) {
      float m2 = lm[tid + o2], s2 = ls[tid + o2];
      float nm = fmaxf(lm[tid], m2);
      ls[tid] = ls[tid] * __expf(lm[tid] - nm) + s2 * __expf(m2 - nm);
      lm[tid] = nm;
    }
    __syncthreads();
  }
  if (tid == 0) lvs = lm[0] + logf(ls[0]);
  __syncthreads();
  float Lv = lvs;
  for (int i = tid; i < 6282; i += 512) {
    short8 sv = *(const short8*)(srow + i * 8);
    float4 v0, v1;
    v0.x = b2f((unsigned short)sv[0]) - Lv; v0.y = b2f((unsigned short)sv[1]) - Lv;
    v0.z = b2f((unsigned short)sv[2]) - Lv; v0.w = b2f((unsigned short)sv[3]) - Lv;
    v1.x = b2f((unsigned short)sv[4]) - Lv; v1.y = b2f((unsigned short)sv[5]) - Lv;
    v1.z = b2f((unsigned short)sv[6]) - Lv; v1.w = b2f((unsigned short)sv[7]) - Lv;
    *(float4*)(o + i * 8) = v0;
    *(float4*)(o + i * 8 + 4) = v1;
  }
  if (tid == 0) o[50256] = b2f(srow[50256]) - Lv;
}

__global__ __launch_bounds__(256) void k_lsefin0(float* __restrict__ out) {
  __shared__ float lm[256], ls[256];
  __shared__ float lvs;
  int bid = blockIdx.x;
  int tid = threadIdx.x;
  if (bid >= NROW) {
    int b = bid - NROW;
    float* o = out + (size_t)b * T_ * V_;
    for (int v = tid; v < V_; v += 256) o[v] = 0.f;
    return;
  }
  int rho = bid;
  int tp = rho >> 6, b = rho & 63;
  float* o = out + ((size_t)b * T_ + (tp + 1)) * V_;
  float m = -1e30f, s = 0.f;
  for (int v = tid; v < V_; v += 256) {
    float x = o[v];
    float nm = fmaxf(m, x);
    s = s * __expf(m - nm) + __expf(x - nm);
    m = nm;
  }
  lm[tid] = m; ls[tid] = s;
  __syncthreads();
  for (int o2 = 128; o2 > 0; o2 >>= 1) {
    if (tid < o2) {
      float m2 = lm[tid + o2], s2 = ls[tid + o2];
      float nm = fmaxf(lm[tid], m2);
      ls[tid] = ls[tid] * __expf(lm[tid] - nm) + s2 * __expf(m2 - nm);
      lm[tid] = nm;
    }
    __syncthreads();
  }
  if (tid == 0) lvs = lm[0] + logf(ls[0]);
  __syncthreads();
  float Lv = lvs;
  for (int v = tid; v < V_; v += 256) o[v] -= Lv;
}

/* ---------------- host ---------------- */

extern "C" void kernel_launch(void* const* d_in, const int* in_sizes, int n_in,
                              void* d_out, int out_size, void* d_ws, size_t ws_size,
                              hipStream_t stream) {
  const float* enc   = (const float*)d_in[0];
  const float* dih   = (const float*)d_in[1];
  const float* mask  = (const float*)d_in[2];
  const float* et    = (const float*)d_in[4];
  const float* Wih   = (const float*)d_in[5];
  const float* Whh   = (const float*)d_in[6];
  const float* bih   = (const float*)d_in[7];
  const float* bhh   = (const float*)d_in[8];
  const float* Waenc = (const float*)d_in[9];
  const float* Wah   = (const float*)d_in[10];
  const float* vatt  = (const float*)d_in[11];
  const float* Wout  = (const float*)d_in[12];
  const float* bout  = (const float*)d_in[13];
  const int*   ref   = (const int*)d_in[14];
  float* out = (float*)d_out;

  char* w = (char*)d_ws;
  size_t o = 0;
  unsigned short* Wb    = (unsigned short*)(w + o); o += (size_t)V_ * H_ * 2;
  unsigned short* Wfih  = (unsigned short*)(w + o); o += (size_t)1536 * 1024 * 2;
  unsigned short* Wfhh  = (unsigned short*)(w + o); o += (size_t)1536 * 512 * 2;
  unsigned short* WaTb  = (unsigned short*)(w + o); o += (size_t)512 * 512 * 2;
  unsigned short* Wahf  = (unsigned short*)(w + o); o += (size_t)512 * 512 * 2;
  float* WahT32 = (float*)(w + o); o += (size_t)512 * 512 * 4;
  unsigned short* encb  = (unsigned short*)(w + o); o += (size_t)B_ * L_ * F_ * 2;
  unsigned short* epb   = (unsigned short*)(w + o); o += (size_t)B_ * L_ * A_ * 2;
  unsigned short* xAll  = (unsigned short*)(w + o); o += (size_t)20 * BD * 2;
  unsigned short* hsAll = (unsigned short*)(w + o); o += (size_t)T_ * BH * 2;
  float* hBAll = (float*)(w + o); o += (size_t)T_ * BH * 4;
  float* ghG   = (float*)(w + o); o += (size_t)1536 * B_ * 4;
  float* hw    = (float*)(w + o); o += (size_t)B_ * A_ * 4;
  unsigned int* cnt = (unsigned int*)(w + o); o += 256;
  unsigned short* lws = (unsigned short*)(w + o);
  size_t need = o + (size_t)NROW * PADV * 2;
  int mode = (ws_size >= need) ? 1 : 0;

  k_setupA<<<7808, 256, 0, stream>>>(Wout, Wb, enc, encb, Wih, Wfih, Whh, Wfhh,
                                     Waenc, WaTb, Wah, WahT32, dih, hsAll, ref, et, xAll);
  k_setupB<<<232, 256, 0, stream>>>(WahT32, Wahf, encb, WaTb, epb, cnt);

  RecPP rp;
  rp.mask = mask; rp.vatt = vatt;
  rp.encb = encb; rp.epb = epb;
  rp.Wahf = Wahf; rp.Wfhh = Wfhh; rp.Wfih = Wfih;
  rp.bih = bih; rp.bhh = bhh;
  rp.dih = dih;
  rp.hsAll = hsAll; rp.hBAll = hBAll; rp.xAll = xAll;
  rp.hw = hw; rp.ghG = ghG;
  rp.cnt = cnt;
  void* args[] = {&rp};
  hipError_t err = hipLaunchCooperativeKernel((const void*)k_rec2, dim3(NBP), dim3(512),
                                              args, 0, stream);
  if (err != hipSuccess) {
    for (int t = 0; t < T_ - 1; ++t) {
      const float* hB_t = (t == 0) ? dih : (hBAll + (size_t)t * BH);
      float* hB_n = hBAll + (size_t)(t + 1) * BH;
      const unsigned short* hs_t = hsAll + (size_t)t * BH;
      unsigned short* hs_n = hsAll + (size_t)(t + 1) * BH;
      unsigned short* xp = xAll + (size_t)t * BD;
      k_hwgh<<<128, 256, 0, stream>>>(Wahf, Wfhh, hs_t, hw, ghG);
      k_attB<<<64, 1024, 0, stream>>>(mask, vatt, encb, epb, hw, xp);
      k_stepB<<<32, 256, 0, stream>>>(Wfih, bih, bhh, xp, ghG, hB_t, hs_n, hB_n);
    }
  }
  k_blog<<<NBLK32, 256, 0, stream>>>(Wb, bout, hsAll, out, lws, mode);
  if (mode == 1) k_lsefin<<<NROW + 64, 512, 0, stream>>>(lws, out);
  else k_lsefin0<<<NROW + 64, 256, 0, stream>>>(out);
}

// Round 21
// 1303.749 us; speedup vs baseline: 1.3157x; 1.3157x over previous
//
#include <hip/hip_runtime.h>
#include <stdint.h>
#include <stddef.h>

#define B_ 64
#define L_ 200
#define F_ 512
#define H_ 512
#define A_ 512
#define E_ 512
#define V_ 50257
#define PADV 50304
#define T_ 21
#define D_ 1024
#define NBLK32 1572
#define BH (B_ * H_)
#define BD (B_ * D_)
#define NROW 1280

typedef __attribute__((ext_vector_type(8))) short short8;
typedef __attribute__((ext_vector_type(4))) float f32x4;

__device__ __forceinline__ unsigned short f2b(float f) {
  unsigned int u = __builtin_bit_cast(unsigned int, f);
  u += 0x7FFFu + ((u >> 16) & 1u);
  return (unsigned short)(u >> 16);
}
__device__ __forceinline__ float b2f(unsigned short s) {
  unsigned int u = ((unsigned int)s) << 16;
  return __builtin_bit_cast(float, u);
}
__device__ __forceinline__ f32x4 mfma16(short8 a, short8 b, f32x4 c) {
  return __builtin_amdgcn_mfma_f32_16x16x32_bf16(a, b, c, 0, 0, 0);
}
__device__ __forceinline__ int hsoff(int b, int j) {
  return (((b >> 4) * 16 + (j >> 5)) * 64 + (((j >> 3) & 3) * 16 + (b & 15))) * 8 + (j & 7);
}
__device__ __forceinline__ int xoff(int b, int k) {
  return (((b >> 4) * 32 + (k >> 5)) * 64 + (((k >> 3) & 3) * 16 + (b & 15))) * 8 + (k & 7);
}

/* ---------------- setup device helpers ---------------- */

__device__ void cvt_dev(const float* __restrict__ src, unsigned short* __restrict__ dst,
                        int n4, int vbid, int nblk) {
  int i = vbid * 256 + threadIdx.x;
  int stride = nblk * 256;
  const float4* s4 = (const float4*)src;
  ushort4* d4 = (ushort4*)dst;
  for (; i < n4; i += stride) {
    float4 v = s4[i];
    ushort4 o;
    o.x = f2b(v.x); o.y = f2b(v.y); o.z = f2b(v.z); o.w = f2b(v.w);
    d4[i] = o;
  }
}

__device__ void wfrag_dev(const float* __restrict__ src, unsigned short* __restrict__ dst,
                          int K, int rt) {
  int r15 = threadIdx.x & 15;
  int row = rt * 16 + r15;
  int nch = K >> 3;
  int kpw = K >> 5;
  for (int kc = threadIdx.x >> 4; kc < nch; kc += 16) {
    const float4* s = (const float4*)(src + (size_t)row * K + kc * 8);
    float4 x = s[0], y = s[1];
    short8 o;
    o[0] = f2b(x.x); o[1] = f2b(x.y); o[2] = f2b(x.z); o[3] = f2b(x.w);
    o[4] = f2b(y.x); o[5] = f2b(y.y); o[6] = f2b(y.z); o[7] = f2b(y.w);
    *(short8*)(dst + ((size_t)(rt * kpw + (kc >> 2)) * 64 + ((kc & 3) * 16 + r15)) * 8) = o;
  }
}

/* ---------------- stage-A mega setup (r18 verified) ---------------- */
__global__ __launch_bounds__(256) void k_setupA(const float* __restrict__ Wout, unsigned short* __restrict__ Wb,
                                                const float* __restrict__ enc, unsigned short* __restrict__ encb,
                                                const float* __restrict__ Wih, unsigned short* __restrict__ Wfih,
                                                const float* __restrict__ Whh, unsigned short* __restrict__ Wfhh,
                                                const float* __restrict__ Waenc, unsigned short* __restrict__ WaTb,
                                                const float* __restrict__ Wah, float* __restrict__ WahT32,
                                                const float* __restrict__ dih, unsigned short* __restrict__ hsAll,
                                                const int* __restrict__ ref, const float* __restrict__ et,
                                                unsigned short* __restrict__ xAll) {
  __shared__ float tile[64][65];
  int bid = blockIdx.x;
  int tid = threadIdx.x;
  if (bid < 4096) {
    cvt_dev(Wout, Wb, V_ * H_ / 4, bid, 4096);
  } else if (bid < 6144) {
    cvt_dev(enc, encb, B_ * L_ * F_ / 4, bid - 4096, 2048);
  } else if (bid < 6240) {
    wfrag_dev(Wih, Wfih, 1024, bid - 6144);
  } else if (bid < 6336) {
    wfrag_dev(Whh, Wfhh, 512, bid - 6240);
  } else if (bid < 6400) {
    int q = bid - 6336;
    int cb = (q & 7) * 64, rb = (q >> 3) * 64;
    int tx = tid & 63, ty = tid >> 6;
#pragma unroll
    for (int i = 0; i < 16; ++i) {
      int r = ty * 16 + i;
      tile[r][tx] = Waenc[(size_t)(rb + r) * 512 + cb + tx];
    }
    __syncthreads();
#pragma unroll
    for (int i = 0; i < 16; ++i) {
      int c = ty * 16 + i;
      WaTb[(size_t)(cb + c) * 512 + rb + tx] = f2b(tile[tx][c]);
    }
  } else if (bid < 6464) {
    int q = bid - 6400;
    int cb = (q & 7) * 64, rb = (q >> 3) * 64;
    int tx = tid & 63, ty = tid >> 6;
#pragma unroll
    for (int i = 0; i < 16; ++i) {
      int r = ty * 16 + i;
      tile[r][tx] = Wah[(size_t)(rb + r) * 512 + cb + tx];
    }
    __syncthreads();
#pragma unroll
    for (int i = 0; i < 16; ++i) {
      int c = ty * 16 + i;
      WahT32[(size_t)(cb + c) * 512 + rb + tx] = tile[tx][c];
    }
  } else if (bid < 6528) {
    int b = bid - 6464;
    for (int j = tid; j < H_; j += 256)
      hsAll[hsoff(b, j)] = f2b(dih[(size_t)b * H_ + j]);
  } else {
    int q = bid - 6528;
    int b = q & 63, tp = q >> 6;
    if (tid < 64) {
      int word = ref[b * T_ + tp];
      const float* er = et + (size_t)word * E_;
      unsigned short* dst = xAll + (size_t)tp * BD;
      int c = tid;
      const float4* s = (const float4*)(er + c * 8);
      float4 x = s[0], y = s[1];
      short8 o;
      o[0] = f2b(x.x); o[1] = f2b(x.y); o[2] = f2b(x.z); o[3] = f2b(x.w);
      o[4] = f2b(y.x); o[5] = f2b(y.y); o[6] = f2b(y.z); o[7] = f2b(y.w);
      *(short8*)(dst + xoff(b, c * 8)) = o;
    }
  }
}

/* ---------------- stage-B setup (r18 verified) ---------------- */
__global__ __launch_bounds__(256) void k_setupB(const float* __restrict__ WahT32,
                                                unsigned short* __restrict__ Wahf,
                                                const unsigned short* __restrict__ encb,
                                                const unsigned short* __restrict__ WaTb,
                                                unsigned short* __restrict__ epb) {
  __shared__ unsigned short al[32768];
  int bid = blockIdx.x;
  int tid = threadIdx.x;
  if (bid < 32) {
    wfrag_dev(WahT32, Wahf, 512, bid);
    return;
  }
  size_t rowbase = (size_t)(bid - 32) * 64;
  for (int idx = tid; idx < 4096; idx += 256) {
    int row = idx >> 6, seg = idx & 63;
    unsigned char* dp = (unsigned char*)al + row * 1024 + ((seg * 16) ^ ((row & 7) << 4));
    *(short8*)dp = *(const short8*)(encb + (rowbase + row) * F_ + seg * 8);
  }
  __syncthreads();
  int w = tid >> 6, lane = tid & 63, ln15 = lane & 15, g = lane >> 4;
  int sw = (ln15 & 7) << 4;
  const unsigned char* alb = (const unsigned char*)al;
  int mrow = w * 16 + ln15;
  for (int nt = 0; nt < 32; ++nt) {
    f32x4 acc = {0.f, 0.f, 0.f, 0.f};
    const unsigned short* brow = WaTb + (size_t)(nt * 16 + ln15) * F_ + 8 * g;
#pragma unroll 4
    for (int kk = 0; kk < 16; ++kk) {
      short8 bf = *(const short8*)(brow + kk * 32);
      short8 af = *(const short8*)(alb + mrow * 1024 + ((kk * 64 + 16 * g) ^ sw));
      acc = mfma16(af, bf, acc);
    }
#pragma unroll
    for (int r = 0; r < 4; ++r) {
      size_t m = rowbase + w * 16 + 4 * g + r;
      epb[m * A_ + nt * 16 + ln15] = f2b(acc[r]);
    }
  }
}

/* ---------------- per-step K1: hw MFMA (0..31) || gh MFMA (32..127) ---------------- */

__global__ __launch_bounds__(256) void k_hwgh(const unsigned short* __restrict__ Wahf,
                                              const unsigned short* __restrict__ Wfhh,
                                              const unsigned short* __restrict__ hs,
                                              float* __restrict__ hw,
                                              float* __restrict__ ghG) {
  int blk = blockIdx.x;
  int w = threadIdx.x >> 6, lane = threadIdx.x & 63;
  int ln15 = lane & 15, g = lane >> 4;
  if (blk < 32) {
    f32x4 acc = {0.f, 0.f, 0.f, 0.f};
#pragma unroll 4
    for (int kk = 0; kk < 16; ++kk) {
      short8 av = *(const short8*)(Wahf + (((size_t)blk * 16 + kk) * 64 + lane) * 8);
      short8 hv = *(const short8*)(hs + (((size_t)w * 16 + kk) * 64 + lane) * 8);
      acc = mfma16(av, hv, acc);
    }
#pragma unroll
    for (int r = 0; r < 4; ++r) {
      int a = blk * 16 + 4 * g + r;
      int b = w * 16 + ln15;
      hw[(size_t)b * 512 + a] = acc[r];
    }
  } else {
    int jt = blk - 32;
    f32x4 acc = {0.f, 0.f, 0.f, 0.f};
#pragma unroll
    for (int kk = 0; kk < 16; ++kk) {
      short8 wv = *(const short8*)(Wfhh + (((size_t)jt * 16 + kk) * 64 + lane) * 8);
      short8 hv = *(const short8*)(hs + (((size_t)w * 16 + kk) * 64 + lane) * 8);
      acc = mfma16(wv, hv, acc);
    }
#pragma unroll
    for (int r = 0; r < 4; ++r) {
      int j = jt * 16 + 4 * g + r;
      int b = w * 16 + ln15;
      ghG[(size_t)j * B_ + b] = acc[r];
    }
  }
}

/* ---------------- per-step K2: fused score+softmax+ctx (r12 verified) ---------------- */

__global__ __launch_bounds__(1024) void k_attB(const float* __restrict__ mask,
                                               const float* __restrict__ vatt,
                                               const unsigned short* __restrict__ encb,
                                               const unsigned short* __restrict__ epb,
                                               const float* __restrict__ hw,
                                               unsigned short* __restrict__ xplane) {
  __shared__ float sm[208];
  __shared__ float ctxp[16][F_];
  __shared__ float ctxF[F_];
  int b = blockIdx.x;
  int tid = threadIdx.x;
  int w = tid >> 6, lane = tid & 63;
  float hwv[8], vv[8];
  {
    const float4* hp = (const float4*)(hw + (size_t)b * 512 + lane * 8);
    const float4* vp = (const float4*)(vatt + lane * 8);
    float4 h0 = hp[0], h1 = hp[1], v0 = vp[0], v1 = vp[1];
    hwv[0] = h0.x; hwv[1] = h0.y; hwv[2] = h0.z; hwv[3] = h0.w;
    hwv[4] = h1.x; hwv[5] = h1.y; hwv[6] = h1.z; hwv[7] = h1.w;
    vv[0] = v0.x; vv[1] = v0.y; vv[2] = v0.z; vv[3] = v0.w;
    vv[4] = v1.x; vv[5] = v1.y; vv[6] = v1.z; vv[7] = v1.w;
  }
  for (int l = w; l < L_; l += 16) {
    short8 ev = *(const short8*)(epb + ((size_t)(b * L_ + l)) * 512 + lane * 8);
    float p = 0.f;
#pragma unroll
    for (int j = 0; j < 8; ++j) {
      float x = b2f((unsigned short)ev[j]) + hwv[j];
      float e2 = __expf(x + x);
      p = fmaf(1.f - 2.f / (e2 + 1.f), vv[j], p);
    }
    for (int o = 1; o < 64; o <<= 1) p += __shfl_xor(p, o);
    if (lane == 0) {
      float mk = mask[b * L_ + l];
      sm[l] = (mk > 0.f) ? p : -1e9f;
    }
  }
  __syncthreads();
  if (tid < 64) {
    float m = -1e30f;
    for (int l = tid; l < L_; l += 64) m = fmaxf(m, sm[l]);
    for (int o = 1; o < 64; o <<= 1) m = fmaxf(m, __shfl_xor(m, o));
    float s = 0.f;
    for (int l = tid; l < L_; l += 64) s += __expf(sm[l] - m);
    for (int o = 1; o < 64; o <<= 1) s += __shfl_xor(s, o);
    float inv = 1.f / s;
    for (int l = tid; l < L_; l += 64) sm[l] = __expf(sm[l] - m) * inv;
  }
  __syncthreads();
  float c[8] = {0.f, 0.f, 0.f, 0.f, 0.f, 0.f, 0.f, 0.f};
  for (int l = w; l < L_; l += 16) {
    float wgt = sm[l];
    short8 ev = *(const short8*)(encb + ((size_t)(b * L_ + l)) * 512 + lane * 8);
#pragma unroll
    for (int j = 0; j < 8; ++j) c[j] = fmaf(wgt, b2f((unsigned short)ev[j]), c[j]);
  }
#pragma unroll
  for (int j = 0; j < 8; ++j) ctxp[w][lane * 8 + j] = c[j];
  __syncthreads();
  if (tid < 512) {
    float s = 0.f;
#pragma unroll
    for (int q = 0; q < 16; ++q) s += ctxp[q][tid];
    ctxF[tid] = s;
  }
  __syncthreads();
  if (tid < 64) {
    short8 o;
#pragma unroll
    for (int j = 0; j < 8; ++j) o[j] = f2b(ctxF[tid * 8 + j]);
    *(short8*)(xplane + xoff(b, E_ + tid * 8)) = o;
  }
}

/* ---------------- per-step K3: gi MFMA + gates (r13 verified) ---------------- */

__global__ __launch_bounds__(256) void k_stepB(const unsigned short* __restrict__ Wfih,
                                               const float* __restrict__ bih,
                                               const float* __restrict__ bhh,
                                               const unsigned short* __restrict__ xplane,
                                               const float* __restrict__ ghG,
                                               const float* __restrict__ hBold,
                                               unsigned short* __restrict__ hsnew,
                                               float* __restrict__ hBnew) {
  int bx = blockIdx.x;
  int w = threadIdx.x >> 6, lane = threadIdx.x & 63;
  int ln15 = lane & 15, g = lane >> 4;
  f32x4 z4 = {0.f, 0.f, 0.f, 0.f};
  f32x4 aIr = z4, aIz = z4, aIn = z4;
#pragma unroll 2
  for (int kk = 0; kk < 32; ++kk) {
    short8 xv = *(const short8*)(xplane + (((size_t)w * 32 + kk) * 64 + lane) * 8);
    aIr = mfma16(*(const short8*)(Wfih + (((size_t)(0 * 32 + bx) * 32 + kk) * 64 + lane) * 8), xv, aIr);
    aIz = mfma16(*(const short8*)(Wfih + (((size_t)(32 + bx) * 32 + kk) * 64 + lane) * 8), xv, aIz);
    aIn = mfma16(*(const short8*)(Wfih + (((size_t)(64 + bx) * 32 + kk) * 64 + lane) * 8), xv, aIn);
  }
  int jb = bx * 16;
#pragma unroll
  for (int r = 0; r < 4; ++r) {
    int j = jb + 4 * g + r;
    int b = w * 16 + ln15;
    float ir = aIr[r] + bih[j];
    float iz = aIz[r] + bih[512 + j];
    float in_ = aIn[r] + bih[1024 + j];
    float hrv = ghG[(size_t)j * B_ + b] + bhh[j];
    float hzv = ghG[(size_t)(512 + j) * B_ + b] + bhh[512 + j];
    float hnv = ghG[(size_t)(1024 + j) * B_ + b] + bhh[1024 + j];
    float rg = 1.f / (1.f + __expf(-(ir + hrv)));
    float zg = 1.f / (1.f + __expf(-(iz + hzv)));
    float e2 = __expf(2.f * (in_ + rg * hnv));
    float ng = 1.f - 2.f / (e2 + 1.f);
    float ho = hBold[(size_t)b * H_ + j];
    float hv = (1.f - zg) * ng + zg * ho;
    hBnew[(size_t)b * H_ + j] = hv;
    hsnew[hsoff(b, j)] = f2b(hv);
  }
}

/* ---------------- logits GEMM: 32-col tiles, 1572 blocks, bf16 LDS dbuf ---------------- */

__global__ __launch_bounds__(256) void k_blog(const unsigned short* __restrict__ Wb,
                                              const float* __restrict__ bout,
                                              const unsigned short* __restrict__ hsAll,
                                              float* __restrict__ out,
                                              unsigned short* __restrict__ lws, int mode) {
  __shared__ unsigned short tile[2][64][40];
  int tid = threadIdx.x;
  int w = tid >> 6, lane = tid & 63, ln15 = lane & 15, g = lane >> 4;
  int ch = w & 1, mh = w >> 1;
  int vcol = blockIdx.x * 32 + ch * 16 + ln15;
  bool vok = vcol < V_;
  int vr = vok ? vcol : (V_ - 1);
  const unsigned short* brow = Wb + (size_t)vr * H_ + 8 * g;
  short8 wb[16];
#pragma unroll
  for (int kk = 0; kk < 16; ++kk) wb[kk] = *(const short8*)(brow + kk * 32);
  float bo = bout[vr];
  int row = tid >> 2, seg = tid & 3;

  for (int t = 0; t < T_ - 1; ++t) {
    const unsigned short* hp = hsAll + (size_t)(t + 1) * BH;
    int buf = t & 1;
    __builtin_amdgcn_s_setprio(1);
    f32x4 z4 = {0.f, 0.f, 0.f, 0.f};
    f32x4 acc0 = z4, acc1 = z4;
#pragma unroll
    for (int kk = 0; kk < 16; ++kk) {
      short8 a0 = *(const short8*)(hp + (((mh * 2 + 0) * 16 + kk) * 64 + lane) * 8);
      short8 a1 = *(const short8*)(hp + (((mh * 2 + 1) * 16 + kk) * 64 + lane) * 8);
      acc0 = mfma16(a0, wb[kk], acc0);
      acc1 = mfma16(a1, wb[kk], acc1);
    }
    __builtin_amdgcn_s_setprio(0);
#pragma unroll
    for (int r = 0; r < 4; ++r) {
      int bi0 = (mh * 2 + 0) * 16 + 4 * g + r;
      int bi1 = (mh * 2 + 1) * 16 + 4 * g + r;
      int col = ch * 16 + ln15;
      tile[buf][bi0][col] = vok ? f2b(acc0[r] + bo) : f2b(-1e30f);
      tile[buf][bi1][col] = vok ? f2b(acc1[r] + bo) : f2b(-1e30f);
    }
    __syncthreads();
    int cb = blockIdx.x * 32 + seg * 8;
    if (mode == 1) {
      short8 sv = *(const short8*)&tile[buf][row][seg * 8];
      *(short8*)(lws + ((size_t)t * 64 + row) * PADV + cb) = sv;
    } else {
      short8 sv = *(const short8*)&tile[buf][row][seg * 8];
      float* orow = out + ((size_t)row * T_ + (t + 1)) * V_ + cb;
      if (cb + 8 <= V_) {
#pragma unroll
        for (int i = 0; i < 8; ++i) orow[i] = b2f((unsigned short)sv[i]);
      } else {
        for (int i = 0; i < 8; ++i)
          if (cb + i < V_) orow[i] = b2f((unsigned short)sv[i]);
      }
    }
  }
}

/* ---------------- fused LSE + finalize + plane0 zero (r16 verified) ---------------- */

__global__ __launch_bounds__(512) void k_lsefin(const unsigned short* __restrict__ lws,
                                                float* __restrict__ out) {
  __shared__ unsigned short srow[PADV];
  __shared__ float lm[512], ls[512];
  __shared__ float lvs;
  int bid = blockIdx.x;
  int tid = threadIdx.x;
  if (bid >= NROW) {
    int b = bid - NROW;
    float* o = out + (size_t)b * T_ * V_;
    float4 z = make_float4(0.f, 0.f, 0.f, 0.f);
    for (int i = tid; i < 12564; i += 512) *(float4*)(o + i * 4) = z;
    if (tid == 0) o[50256] = 0.f;
    return;
  }
  int rho = bid;
  int tp = rho >> 6, b = rho & 63;
  const unsigned short* src = lws + (size_t)(tp * 64 + b) * PADV;
  float* o = out + ((size_t)b * T_ + (tp + 1)) * V_;
  float m = -1e30f, s = 0.f;
  for (int i = tid; i < PADV / 8; i += 512) {
    short8 sv = *(const short8*)(src + i * 8);
    *(short8*)(srow + i * 8) = sv;
    float x0 = b2f((unsigned short)sv[0]), x1 = b2f((unsigned short)sv[1]);
    float x2 = b2f((unsigned short)sv[2]), x3 = b2f((unsigned short)sv[3]);
    float x4 = b2f((unsigned short)sv[4]), x5 = b2f((unsigned short)sv[5]);
    float x6 = b2f((unsigned short)sv[6]), x7 = b2f((unsigned short)sv[7]);
    float cm = fmaxf(fmaxf(fmaxf(x0, x1), fmaxf(x2, x3)), fmaxf(fmaxf(x4, x5), fmaxf(x6, x7)));
    float cs = __expf(x0 - cm) + __expf(x1 - cm) + __expf(x2 - cm) + __expf(x3 - cm) +
               __expf(x4 - cm) + __expf(x5 - cm) + __expf(x6 - cm) + __expf(x7 - cm);
    float nm = fmaxf(m, cm);
    s = s * __expf(m - nm) + cs * __expf(cm - nm);
    m = nm;
  }
  lm[tid] = m; ls[tid] = s;
  __syncthreads();
  for (int o2 = 256; o2 > 0; o2 >>= 1) {
    if (tid < o2) {
      float m2 = lm[tid + o2], s2 = ls[tid + o2];
      float nm = fmaxf(lm[tid], m2);
      ls[tid] = ls[tid] * __expf(lm[tid] - nm) + s2 * __expf(m2 - nm);
      lm[tid] = nm;
    }
    __syncthreads();
  }
  if (tid == 0) lvs = lm[0] + logf(ls[0]);
  __syncthreads();
  float Lv = lvs;
  for (int i = tid; i < 6282; i += 512) {
    short8 sv = *(const short8*)(srow + i * 8);
    float4 v0, v1;
    v0.x = b2f((unsigned short)sv[0]) - Lv; v0.y = b2f((unsigned short)sv[1]) - Lv;
    v0.z = b2f((unsigned short)sv[2]) - Lv; v0.w = b2f((unsigned short)sv[3]) - Lv;
    v1.x = b2f((unsigned short)sv[4]) - Lv; v1.y = b2f((unsigned short)sv[5]) - Lv;
    v1.z = b2f((unsigned short)sv[6]) - Lv; v1.w = b2f((unsigned short)sv[7]) - Lv;
    *(float4*)(o + i * 8) = v0;
    *(float4*)(o + i * 8 + 4) = v1;
  }
  if (tid == 0) o[50256] = b2f(srow[50256]) - Lv;
}

__global__ __launch_bounds__(256) void k_lsefin0(float* __restrict__ out) {
  __shared__ float lm[256], ls[256];
  __shared__ float lvs;
  int bid = blockIdx.x;
  int tid = threadIdx.x;
  if (bid >= NROW) {
    int b = bid - NROW;
    float* o = out + (size_t)b * T_ * V_;
    for (int v = tid; v < V_; v += 256) o[v] = 0.f;
    return;
  }
  int rho = bid;
  int tp = rho >> 6, b = rho & 63;
  float* o = out + ((size_t)b * T_ + (tp + 1)) * V_;
  float m = -1e30f, s = 0.f;
  for (int v = tid; v < V_; v += 256) {
    float x = o[v];
    float nm = fmaxf(m, x);
    s = s * __expf(m - nm) + __expf(x - nm);
    m = nm;
  }
  lm[tid] = m; ls[tid] = s;
  __syncthreads();
  for (int o2 = 128; o2 > 0; o2 >>= 1) {
    if (tid < o2) {
      float m2 = lm[tid + o2], s2 = ls[tid + o2];
      float nm = fmaxf(lm[tid], m2);
      ls[tid] = ls[tid] * __expf(lm[tid] - nm) + s2 * __expf(m2 - nm);
      lm[tid] = nm;
    }
    __syncthreads();
  }
  if (tid == 0) lvs = lm[0] + logf(ls[0]);
  __syncthreads();
  float Lv = lvs;
  for (int v = tid; v < V_; v += 256) o[v] -= Lv;
}

/* ---------------- host ---------------- */

extern "C" void kernel_launch(void* const* d_in, const int* in_sizes, int n_in,
                              void* d_out, int out_size, void* d_ws, size_t ws_size,
                              hipStream_t stream) {
  const float* enc   = (const float*)d_in[0];
  const float* dih   = (const float*)d_in[1];
  const float* mask  = (const float*)d_in[2];
  const float* et    = (const float*)d_in[4];
  const float* Wih   = (const float*)d_in[5];
  const float* Whh   = (const float*)d_in[6];
  const float* bih   = (const float*)d_in[7];
  const float* bhh   = (const float*)d_in[8];
  const float* Waenc = (const float*)d_in[9];
  const float* Wah   = (const float*)d_in[10];
  const float* vatt  = (const float*)d_in[11];
  const float* Wout  = (const float*)d_in[12];
  const float* bout  = (const float*)d_in[13];
  const int*   ref   = (const int*)d_in[14];
  float* out = (float*)d_out;

  char* w = (char*)d_ws;
  size_t o = 0;
  unsigned short* Wb    = (unsigned short*)(w + o); o += (size_t)V_ * H_ * 2;
  unsigned short* Wfih  = (unsigned short*)(w + o); o += (size_t)1536 * 1024 * 2;
  unsigned short* Wfhh  = (unsigned short*)(w + o); o += (size_t)1536 * 512 * 2;
  unsigned short* WaTb  = (unsigned short*)(w + o); o += (size_t)512 * 512 * 2;
  unsigned short* Wahf  = (unsigned short*)(w + o); o += (size_t)512 * 512 * 2;
  float* WahT32 = (float*)(w + o); o += (size_t)512 * 512 * 4;
  unsigned short* encb  = (unsigned short*)(w + o); o += (size_t)B_ * L_ * F_ * 2;
  unsigned short* epb   = (unsigned short*)(w + o); o += (size_t)B_ * L_ * A_ * 2;
  unsigned short* xAll  = (unsigned short*)(w + o); o += (size_t)20 * BD * 2;
  unsigned short* hsAll = (unsigned short*)(w + o); o += (size_t)T_ * BH * 2;
  float* hBAll = (float*)(w + o); o += (size_t)T_ * BH * 4;
  float* ghG   = (float*)(w + o); o += (size_t)1536 * B_ * 4;
  float* hw    = (float*)(w + o); o += (size_t)B_ * A_ * 4 + 256;
  unsigned short* lws = (unsigned short*)(w + o);
  size_t need = o + (size_t)NROW * PADV * 2;
  int mode = (ws_size >= need) ? 1 : 0;

  k_setupA<<<7808, 256, 0, stream>>>(Wout, Wb, enc, encb, Wih, Wfih, Whh, Wfhh,
                                     Waenc, WaTb, Wah, WahT32, dih, hsAll, ref, et, xAll);
  k_setupB<<<232, 256, 0, stream>>>(WahT32, Wahf, encb, WaTb, epb);

  for (int t = 0; t < T_ - 1; ++t) {
    const float* hB_t = (t == 0) ? dih : (hBAll + (size_t)t * BH);
    float* hB_n = hBAll + (size_t)(t + 1) * BH;
    const unsigned short* hs_t = hsAll + (size_t)t * BH;
    unsigned short* hs_n = hsAll + (size_t)(t + 1) * BH;
    unsigned short* xp = xAll + (size_t)t * BD;
    k_hwgh<<<128, 256, 0, stream>>>(Wahf, Wfhh, hs_t, hw, ghG);
    k_attB<<<64, 1024, 0, stream>>>(mask, vatt, encb, epb, hw, xp);
    k_stepB<<<32, 256, 0, stream>>>(Wfih, bih, bhh, xp, ghG, hB_t, hs_n, hB_n);
  }
  k_blog<<<NBLK32, 256, 0, stream>>>(Wb, bout, hsAll, out, lws, mode);
  if (mode == 1) k_lsefin<<<NROW + 64, 512, 0, stream>>>(lws, out);
  else k_lsefin0<<<NROW + 64, 256, 0, stream>>>(out);
}